// Round 1
// baseline (604.893 us; speedup 1.0000x reference)
//
#include <hip/hip_runtime.h>
#include <math.h>

// RechitsGCN fused kernel — round 1 (fp32 correctness baseline).
// One workgroup per (b,c) group; all 128x128 intermediates live in LDS.
#define Bb 16
#define Cc 64
#define Rr 128
#define Ff 18
#define Hh 128
#define Gg (Bb*Cc)
#define LDA 132      // pad 128->132 floats: breaks power-of-2 bank strides
#define NT 512
#define XSTR 20      // x tile row stride (18 -> 20)

// ---- chunked (global-weight) matmul: acc[4][8] += A[r0..r0+3][k] * W[k][h0..h0+7]
// W staged through a 16x128 LDS chunk; ALL threads must call (internal barriers).
static __device__ __forceinline__ void wchunk_mm(
    float acc[4][8], const float* __restrict__ Aop, const int lda, const int aR0,
    const float* __restrict__ Wg, const int K, float* __restrict__ WB,
    const int tid, const int h0)
{
  for (int k0 = 0; k0 < K; k0 += 16) {
    const int kn = (K - k0 < 16) ? (K - k0) : 16;
    __syncthreads();                       // previous chunk fully consumed
    for (int i = tid; i < kn * (Hh/4); i += NT)
      ((float4*)WB)[i] = ((const float4*)(Wg + (size_t)k0 * Hh))[i];
    __syncthreads();
    if (kn == 16) {
      #pragma unroll
      for (int kk = 0; kk < 16; kk++) {
        const int k = k0 + kk;
        const float a0 = Aop[(aR0 + 0) * lda + k];
        const float a1 = Aop[(aR0 + 1) * lda + k];
        const float a2 = Aop[(aR0 + 2) * lda + k];
        const float a3 = Aop[(aR0 + 3) * lda + k];
        const float* wr = &WB[kk * Hh + h0];
        const float4 bA = *(const float4*)(wr);
        const float4 bB = *(const float4*)(wr + 4);
        const float bv[8] = {bA.x, bA.y, bA.z, bA.w, bB.x, bB.y, bB.z, bB.w};
        #pragma unroll
        for (int j = 0; j < 8; j++) {
          acc[0][j] += a0 * bv[j];
          acc[1][j] += a1 * bv[j];
          acc[2][j] += a2 * bv[j];
          acc[3][j] += a3 * bv[j];
        }
      }
    } else {
      for (int kk = 0; kk < kn; kk++) {
        const int k = k0 + kk;
        const float a0 = Aop[(aR0 + 0) * lda + k];
        const float a1 = Aop[(aR0 + 1) * lda + k];
        const float a2 = Aop[(aR0 + 2) * lda + k];
        const float a3 = Aop[(aR0 + 3) * lda + k];
        const float* wr = &WB[kk * Hh + h0];
        const float4 bA = *(const float4*)(wr);
        const float4 bB = *(const float4*)(wr + 4);
        const float bv[8] = {bA.x, bA.y, bA.z, bA.w, bB.x, bB.y, bB.z, bB.w};
        #pragma unroll
        for (int j = 0; j < 8; j++) {
          acc[0][j] += a0 * bv[j];
          acc[1][j] += a1 * bv[j];
          acc[2][j] += a2 * bv[j];
          acc[3][j] += a3 * bv[j];
        }
      }
    }
  }
}

// ---- LDS x LDS matmul: acc[4][8] += A[r0..r0+3][s] * B[s][h0..h0+7], K=128
static __device__ __forceinline__ void lds_mm(
    float acc[4][8], const float* __restrict__ Aop, const int aR0,
    const float* __restrict__ Bop, const int h0)
{
  #pragma unroll 4
  for (int s = 0; s < Rr; s++) {
    const float a0 = Aop[(aR0 + 0) * LDA + s];
    const float a1 = Aop[(aR0 + 1) * LDA + s];
    const float a2 = Aop[(aR0 + 2) * LDA + s];
    const float a3 = Aop[(aR0 + 3) * LDA + s];
    const float* br = &Bop[s * LDA + h0];
    const float4 bA = *(const float4*)(br);
    const float4 bB = *(const float4*)(br + 4);
    const float bv[8] = {bA.x, bA.y, bA.z, bA.w, bB.x, bB.y, bB.z, bB.w};
    #pragma unroll
    for (int j = 0; j < 8; j++) {
      acc[0][j] += a0 * bv[j];
      acc[1][j] += a1 * bv[j];
      acc[2][j] += a2 * bv[j];
      acc[3][j] += a3 * bv[j];
    }
  }
}

// ---- Wqk = wq @ wk^T / sqrt(H)  (tiny: 4.2 MFLOP, runs once before main kernel)
__global__ __launch_bounds__(Hh) void wqk_prep(const float* __restrict__ wq,
                                               const float* __restrict__ wk,
                                               float* __restrict__ wqk)
{
  const int i = blockIdx.x, j = threadIdx.x;
  __shared__ float row[Hh];
  row[j] = wq[i * Hh + j];
  __syncthreads();
  float acc = 0.f;
  for (int a = 0; a < Hh; a++) acc += row[a] * wk[j * Hh + a];
  wqk[i * Hh + j] = acc * 0.08838834764831845f;  // 1/sqrt(128)
}

__global__ void __launch_bounds__(NT, 1)
fused_gcn(const float* __restrict__ x, const float* __restrict__ mask,
          const float* __restrict__ theta, const float* __restrict__ w_t,
          const float* __restrict__ b_t, const float* __restrict__ wqk,
          const float* __restrict__ wv, const float* __restrict__ w1,
          const float* __restrict__ b1, const float* __restrict__ w2,
          const float* __restrict__ b2, const float* __restrict__ g_sa,
          const float* __restrict__ be_sa, const float* __restrict__ g_out,
          const float* __restrict__ be_out, float* __restrict__ out)
{
  extern __shared__ float sm[];
  float* As  = sm;                    // 128*132
  float* Bs  = As + Rr * LDA;         // 128*132
  float* Xs  = Bs + Rr * LDA;         // 128*20
  float* WB  = Xs + Rr * XSTR;        // 16*128 weight chunk
  float* msh = WB + 16 * Hh;          // 128
  float* nk  = msh + Rr;              // 128
  float* sN  = nk + Rr;               // 1 (+7 pad)

  const int g  = blockIdx.x;
  const int tid = threadIdx.x;
  const int rt = tid >> 4;            // 0..31 : 4-row tile
  const int ct = tid & 15;            // 0..15 : 8-col tile
  const int r0 = rt << 2;
  const int h0 = ct << 3;

  const size_t gRH = (size_t)g * Rr * Hh;
  const size_t gRR = (size_t)g * Rr * Rr;
  float* out0  = out;                                                 // (G,H)
  float* sa_o  = out + (size_t)Gg * Hh + gRH;
  float* den_o = out + (size_t)Gg * Hh + (size_t)Gg * Rr * Hh + gRH;
  float* att_o = out + (size_t)Gg * Hh + 2 * (size_t)Gg * Rr * Hh + gRR;
  float* adj_o = out + (size_t)Gg * Hh + 2 * (size_t)Gg * Rr * Hh
                     + (size_t)Gg * Rr * Rr + gRR;

  // ---- S0: stage x tile + mask
  {
    const float* xg = x + (size_t)g * Rr * Ff;
    for (int i = tid; i < Rr * Ff; i += NT) {
      const int r = i / Ff, f = i - r * Ff;
      Xs[r * XSTR + f] = xg[i];
    }
    if (tid < Rr) msh[tid] = mask[(size_t)g * Rr + tid];
  }
  __syncthreads();
  if (tid == 0) { float s = 0.f; for (int r = 0; r < Rr; r++) s += msh[r]; *sN = s; }

  // ---- S1: adj = exp(-sqrt(clip(D^2))) * m_r * m_s ; deg -> nk = (deg+1e-6)^-1.5
  {
    float sc0[8], sc1[8], snv[8], smv[8];
    #pragma unroll
    for (int j = 0; j < 8; j++) {
      const int s = h0 + j;
      sc0[j] = Xs[s * XSTR + 0];
      sc1[j] = Xs[s * XSTR + 1];
      snv[j] = sc0[j] * sc0[j] + sc1[j] * sc1[j];
      smv[j] = msh[s];
    }
    #pragma unroll
    for (int i = 0; i < 4; i++) {
      const int r = r0 + i;
      const float c0 = Xs[r * XSTR + 0], c1 = Xs[r * XSTR + 1];
      const float nr = c0 * c0 + c1 * c1;
      const float mr = msh[r];
      float av[8];
      float dsum = 0.f;
      #pragma unroll
      for (int j = 0; j < 8; j++) {
        float dsq = nr + snv[j] - 2.f * (c0 * sc0[j] + c1 * sc1[j]);
        dsq = fminf(fmaxf(dsq, 1e-12f), 1e12f);
        const float a = expf(-sqrtf(dsq)) * mr * smv[j];
        av[j] = a; dsum += a;
      }
      #pragma unroll
      for (int o = 1; o < 16; o <<= 1) dsum += __shfl_xor(dsum, o);
      if (ct == 0) { const float t = dsum + 1e-6f; nk[r] = 1.f / (t * sqrtf(t)); }
      const float4 v0 = make_float4(av[0], av[1], av[2], av[3]);
      const float4 v1 = make_float4(av[4], av[5], av[6], av[7]);
      *(float4*)&adj_o[(size_t)r * Rr + h0]     = v0;
      *(float4*)&adj_o[(size_t)r * Rr + h0 + 4] = v1;
      *(float4*)&As[r * LDA + h0]     = v0;
      *(float4*)&As[r * LDA + h0 + 4] = v1;
    }
  }
  __syncthreads();   // adj (A) + nk visible to everyone

  // ---- S3: f_het = X @ theta -> B
  {
    float acc[4][8] = {};
    wchunk_mm(acc, Xs, XSTR, r0, theta, Ff, WB, tid, h0);
    #pragma unroll
    for (int i = 0; i < 4; i++) {
      *(float4*)&Bs[(r0 + i) * LDA + h0]     = make_float4(acc[i][0], acc[i][1], acc[i][2], acc[i][3]);
      *(float4*)&Bs[(r0 + i) * LDA + h0 + 4] = make_float4(acc[i][4], acc[i][5], acc[i][6], acc[i][7]);
    }
  }

  // ---- S4: fold A := adj^3 * nk[r] * nk[s]   (wave-private rows)
  {
    #pragma unroll
    for (int i = 0; i < 4; i++) {
      const int r = r0 + i;
      const float nr = nk[r];
      #pragma unroll
      for (int j = 0; j < 8; j++) {
        const int s = h0 + j;
        const float a = As[r * LDA + s];
        As[r * LDA + s] = a * a * a * nr * nk[s];
      }
    }
  }
  __syncthreads();   // f_het (B all rows) + folded A ready

  // ---- S5: f_hom = relu(A' @ f_het); gate = sigmoid(X@w_t + b_t); out_gcn -> A
  {
    float fh[4][8] = {};
    lds_mm(fh, As, r0, Bs, h0);
    float gt[4][8] = {};
    wchunk_mm(gt, Xs, XSTR, r0, w_t, Ff, WB, tid, h0);
    const float4 bt0 = *(const float4*)&b_t[h0];
    const float4 bt1 = *(const float4*)&b_t[h0 + 4];
    const float btv[8] = {bt0.x, bt0.y, bt0.z, bt0.w, bt1.x, bt1.y, bt1.z, bt1.w};
    #pragma unroll
    for (int i = 0; i < 4; i++) {
      float og[8];
      #pragma unroll
      for (int j = 0; j < 8; j++) {
        const float gv  = 1.f / (1.f + expf(-(gt[i][j] + btv[j])));
        const float fhv = fmaxf(fh[i][j], 0.f);
        const float fe  = Bs[(r0 + i) * LDA + h0 + j];
        og[j] = gv * fhv + (1.f - gv) * fe;
      }
      *(float4*)&As[(r0 + i) * LDA + h0]     = make_float4(og[0], og[1], og[2], og[3]);
      *(float4*)&As[(r0 + i) * LDA + h0 + 4] = make_float4(og[4], og[5], og[6], og[7]);
    }
  }

  // ---- S6: t = out_gcn @ (wq wk^T / sqrt(H)) -> B
  {
    float acc[4][8] = {};
    wchunk_mm(acc, As, LDA, r0, wqk, Hh, WB, tid, h0);  // pre-barrier makes og safe
    #pragma unroll
    for (int i = 0; i < 4; i++) {
      *(float4*)&Bs[(r0 + i) * LDA + h0]     = make_float4(acc[i][0], acc[i][1], acc[i][2], acc[i][3]);
      *(float4*)&Bs[(r0 + i) * LDA + h0 + 4] = make_float4(acc[i][4], acc[i][5], acc[i][6], acc[i][7]);
    }
  }
  __syncthreads();

  // ---- S7: logits[r,s] = t[r,:] . og[s,:]; masked softmax -> attn (global + B)
  // s = ct + 16*j interleave: avoids 16-way LDS bank conflict on transposed reads.
  {
    float l[4][8] = {};
    #pragma unroll 2
    for (int h = 0; h < Hh; h++) {
      const float t0 = Bs[(r0 + 0) * LDA + h];
      const float t1 = Bs[(r0 + 1) * LDA + h];
      const float t2 = Bs[(r0 + 2) * LDA + h];
      const float t3 = Bs[(r0 + 3) * LDA + h];
      #pragma unroll
      for (int j = 0; j < 8; j++) {
        const float av = As[(ct + 16 * j) * LDA + h];
        l[0][j] += t0 * av; l[1][j] += t1 * av; l[2][j] += t2 * av; l[3][j] += t3 * av;
      }
    }
    float smv[8];
    #pragma unroll
    for (int j = 0; j < 8; j++) smv[j] = msh[ct + 16 * j];
    #pragma unroll
    for (int i = 0; i < 4; i++) {
      const int r = r0 + i;
      float lv[8]; float mx = -3.4e38f;
      #pragma unroll
      for (int j = 0; j < 8; j++) {
        lv[j] = l[i][j] + (1.f - smv[j]) * (-1e9f);
        mx = fmaxf(mx, lv[j]);
      }
      #pragma unroll
      for (int o = 1; o < 16; o <<= 1) mx = fmaxf(mx, __shfl_xor(mx, o));
      float se = 0.f;
      #pragma unroll
      for (int j = 0; j < 8; j++) { lv[j] = expf(lv[j] - mx); se += lv[j]; }
      #pragma unroll
      for (int o = 1; o < 16; o <<= 1) se += __shfl_xor(se, o);
      const float inv = 1.f / se;
      #pragma unroll
      for (int j = 0; j < 8; j++) {
        const float a = lv[j] * inv;
        const int s = ct + 16 * j;
        att_o[(size_t)r * Rr + s] = a;
        Bs[r * LDA + s] = a;
      }
    }
  }
  __syncthreads();

  // ---- S8: u = attn @ out_gcn -> A (after all og reads complete)
  {
    float u[4][8] = {};
    lds_mm(u, Bs, r0, As, h0);
    __syncthreads();
    #pragma unroll
    for (int i = 0; i < 4; i++) {
      *(float4*)&As[(r0 + i) * LDA + h0]     = make_float4(u[i][0], u[i][1], u[i][2], u[i][3]);
      *(float4*)&As[(r0 + i) * LDA + h0 + 4] = make_float4(u[i][4], u[i][5], u[i][6], u[i][7]);
    }
  }

  // ---- S9: sa = LN(u @ wv) * m_r  -> global + B
  {
    float acc[4][8] = {};
    wchunk_mm(acc, As, LDA, r0, wv, Hh, WB, tid, h0);
    const float4 ga0 = *(const float4*)&g_sa[h0];
    const float4 ga1 = *(const float4*)&g_sa[h0 + 4];
    const float4 ba0 = *(const float4*)&be_sa[h0];
    const float4 ba1 = *(const float4*)&be_sa[h0 + 4];
    const float gav[8] = {ga0.x, ga0.y, ga0.z, ga0.w, ga1.x, ga1.y, ga1.z, ga1.w};
    const float bav[8] = {ba0.x, ba0.y, ba0.z, ba0.w, ba1.x, ba1.y, ba1.z, ba1.w};
    #pragma unroll
    for (int i = 0; i < 4; i++) {
      float s1 = 0.f, s2 = 0.f;
      #pragma unroll
      for (int j = 0; j < 8; j++) { s1 += acc[i][j]; s2 += acc[i][j] * acc[i][j]; }
      #pragma unroll
      for (int o = 1; o < 16; o <<= 1) { s1 += __shfl_xor(s1, o); s2 += __shfl_xor(s2, o); }
      const float mean = s1 * (1.f / 128.f);
      const float var  = s2 * (1.f / 128.f) - mean * mean;
      const float rstd = 1.f / sqrtf(var + 1e-3f);
      const float mr = msh[r0 + i];
      float y[8];
      #pragma unroll
      for (int j = 0; j < 8; j++)
        y[j] = ((acc[i][j] - mean) * rstd * gav[j] + bav[j]) * mr;
      *(float4*)&sa_o[(size_t)(r0 + i) * Hh + h0]     = make_float4(y[0], y[1], y[2], y[3]);
      *(float4*)&sa_o[(size_t)(r0 + i) * Hh + h0 + 4] = make_float4(y[4], y[5], y[6], y[7]);
      *(float4*)&Bs[(r0 + i) * LDA + h0]     = make_float4(y[0], y[1], y[2], y[3]);
      *(float4*)&Bs[(r0 + i) * LDA + h0 + 4] = make_float4(y[4], y[5], y[6], y[7]);
    }
  }

  // ---- S10: d1 = relu(sa @ w1 + b1) -> A
  {
    float acc[4][8] = {};
    wchunk_mm(acc, Bs, LDA, r0, w1, Hh, WB, tid, h0);
    const float4 b10 = *(const float4*)&b1[h0];
    const float4 b11 = *(const float4*)&b1[h0 + 4];
    const float b1v[8] = {b10.x, b10.y, b10.z, b10.w, b11.x, b11.y, b11.z, b11.w};
    #pragma unroll
    for (int i = 0; i < 4; i++) {
      float d[8];
      #pragma unroll
      for (int j = 0; j < 8; j++) d[j] = fmaxf(acc[i][j] + b1v[j], 0.f);
      *(float4*)&As[(r0 + i) * LDA + h0]     = make_float4(d[0], d[1], d[2], d[3]);
      *(float4*)&As[(r0 + i) * LDA + h0 + 4] = make_float4(d[4], d[5], d[6], d[7]);
    }
  }

  // ---- S11: d2 = relu(d1 @ w2 + b2); dense = LN(d2 + sa) * m_r; masked mean-pool
  {
    float acc[4][8] = {};
    wchunk_mm(acc, As, LDA, r0, w2, Hh, WB, tid, h0);
    const float4 b20 = *(const float4*)&b2[h0];
    const float4 b21 = *(const float4*)&b2[h0 + 4];
    const float4 go0 = *(const float4*)&g_out[h0];
    const float4 go1 = *(const float4*)&g_out[h0 + 4];
    const float4 bo0 = *(const float4*)&be_out[h0];
    const float4 bo1 = *(const float4*)&be_out[h0 + 4];
    const float b2v[8] = {b20.x, b20.y, b20.z, b20.w, b21.x, b21.y, b21.z, b21.w};
    const float gov[8] = {go0.x, go0.y, go0.z, go0.w, go1.x, go1.y, go1.z, go1.w};
    const float bov[8] = {bo0.x, bo0.y, bo0.z, bo0.w, bo1.x, bo1.y, bo1.z, bo1.w};
    float dn[4][8];
    #pragma unroll
    for (int i = 0; i < 4; i++) {
      float dd[8];
      #pragma unroll
      for (int j = 0; j < 8; j++)
        dd[j] = fmaxf(acc[i][j] + b2v[j], 0.f) + Bs[(r0 + i) * LDA + h0 + j];
      float s1 = 0.f, s2 = 0.f;
      #pragma unroll
      for (int j = 0; j < 8; j++) { s1 += dd[j]; s2 += dd[j] * dd[j]; }
      #pragma unroll
      for (int o = 1; o < 16; o <<= 1) { s1 += __shfl_xor(s1, o); s2 += __shfl_xor(s2, o); }
      const float mean = s1 * (1.f / 128.f);
      const float var  = s2 * (1.f / 128.f) - mean * mean;
      const float rstd = 1.f / sqrtf(var + 1e-3f);
      const float mr = msh[r0 + i];
      #pragma unroll
      for (int j = 0; j < 8; j++)
        dn[i][j] = ((dd[j] - mean) * rstd * gov[j] + bov[j]) * mr;
      *(float4*)&den_o[(size_t)(r0 + i) * Hh + h0]     = make_float4(dn[i][0], dn[i][1], dn[i][2], dn[i][3]);
      *(float4*)&den_o[(size_t)(r0 + i) * Hh + h0 + 4] = make_float4(dn[i][4], dn[i][5], dn[i][6], dn[i][7]);
    }
    __syncthreads();   // all d1 (A) reads done; A becomes reduction scratch
    #pragma unroll
    for (int j = 0; j < 8; j++)
      As[rt * LDA + h0 + j] = dn[0][j] + dn[1][j] + dn[2][j] + dn[3][j];
    __syncthreads();
    if (tid < Hh) {
      float ssum = 0.f;
      #pragma unroll 8
      for (int q = 0; q < 32; q++) ssum += As[q * LDA + tid];
      const float n = *sN;
      out0[(size_t)g * Hh + tid] = (n > 0.f) ? (ssum / n) : 0.f;
    }
  }
}

extern "C" void kernel_launch(void* const* d_in, const int* in_sizes, int n_in,
                              void* d_out, int out_size, void* d_ws, size_t ws_size,
                              hipStream_t stream) {
  (void)in_sizes; (void)n_in; (void)out_size; (void)ws_size;
  const float* x     = (const float*)d_in[0];
  const float* mask  = (const float*)d_in[1];
  const float* theta = (const float*)d_in[2];
  const float* w_t   = (const float*)d_in[3];
  const float* b_t   = (const float*)d_in[4];
  const float* wq    = (const float*)d_in[5];
  const float* wk    = (const float*)d_in[6];
  const float* wv    = (const float*)d_in[7];
  const float* w1    = (const float*)d_in[8];
  const float* b1    = (const float*)d_in[9];
  const float* w2    = (const float*)d_in[10];
  const float* b2    = (const float*)d_in[11];
  const float* g_sa  = (const float*)d_in[12];
  const float* be_sa = (const float*)d_in[13];
  const float* g_out = (const float*)d_in[14];
  const float* be_out= (const float*)d_in[15];
  float* wqk = (float*)d_ws;   // needs 64 KiB scratch

  wqk_prep<<<dim3(Hh), dim3(Hh), 0, stream>>>(wq, wk, wqk);

  const int smem = (2 * Rr * LDA + Rr * XSTR + 16 * Hh + Rr + Rr + 8) * (int)sizeof(float);
  // 154,656 B dynamic LDS (> 64 KiB) — opt in; idempotent, capture-safe host call.
  (void)hipFuncSetAttribute(reinterpret_cast<const void*>(fused_gcn),
                            hipFuncAttributeMaxDynamicSharedMemorySize, smem);
  fused_gcn<<<dim3(Gg), dim3(NT), smem, stream>>>(
      x, mask, theta, w_t, b_t, wqk, wv, w1, b1, w2, b2,
      g_sa, be_sa, g_out, be_out, (float*)d_out);
}

// Round 2
// 199.715 us; speedup vs baseline: 3.0288x; 3.0288x over previous
//
#include <hip/hip_runtime.h>
#include <math.h>

// RechitsGCN fused kernel — round 2: bf16 MFMA for all six 128^3 matmuls.
// One workgroup (512 thr = 8 waves) per (b,c) group; wave w owns rows 16w..16w+15.
#define Gg 1024
#define NT 512

typedef __bf16 bf16x8 __attribute__((ext_vector_type(8)));
typedef float  f32x4  __attribute__((ext_vector_type(4)));

// ---- LDS byte-offset map (total 146464 B dynamic) ----
#define P_OFF   0        // 32 KB bf16 tile
#define Q_OFF   32768    // 32 KB bf16 tile
#define R_OFF   65536    // 32 KB bf16 tile
#define W_OFF   98304    // 32 KB weight tile (also theta/w_t fp32 early)
#define XS_OFF  131072   // 128x20 f32
#define MSH_OFF 141312   // 128 f32
#define NK_OFF  141824   // 128 f32
#define CS_OFF  142336   // 8x128 f32
#define SN_OFF  146432
#define SMEM_SZ 146464

__device__ __forceinline__ unsigned short f2b(float f){
  unsigned u = __float_as_uint(f);
  u += 0x7FFFu + ((u >> 16) & 1u);
  return (unsigned short)(u >> 16);
}
__device__ __forceinline__ float b2f(unsigned short h){
  return __uint_as_float(((unsigned)h) << 16);
}
// XOR swizzle: spreads rows across 16B slots so stride-256B column access is ~2-way.
__device__ __forceinline__ int SW(int row, int bc){ return (row << 8) + (bc ^ ((row & 7) << 4)); }

__device__ __forceinline__ void unp8(uint4 v, float* o){
  o[0]=b2f((unsigned short)(v.x&0xffffu)); o[1]=b2f((unsigned short)(v.x>>16));
  o[2]=b2f((unsigned short)(v.y&0xffffu)); o[3]=b2f((unsigned short)(v.y>>16));
  o[4]=b2f((unsigned short)(v.z&0xffffu)); o[5]=b2f((unsigned short)(v.z>>16));
  o[6]=b2f((unsigned short)(v.w&0xffffu)); o[7]=b2f((unsigned short)(v.w>>16));
}
__device__ __forceinline__ uint4 pk8(const float* f){
  uint4 v;
  v.x = (unsigned)f2b(f[0]) | ((unsigned)f2b(f[1])<<16);
  v.y = (unsigned)f2b(f[2]) | ((unsigned)f2b(f[3])<<16);
  v.z = (unsigned)f2b(f[4]) | ((unsigned)f2b(f[5])<<16);
  v.w = (unsigned)f2b(f[6]) | ((unsigned)f2b(f[7])<<16);
  return v;
}

__device__ __forceinline__ f32x4 MFMA(uint4 a, uint4 b, f32x4 c){
  return __builtin_amdgcn_mfma_f32_16x16x32_bf16(
      __builtin_bit_cast(bf16x8, a), __builtin_bit_cast(bf16x8, b), c, 0, 0, 0);
}

// D(16x128 strip of wave w) = A(128x128) @ B_storage(128x128)^T ; both bf16 swizzled.
__device__ __forceinline__ void mm_strip(f32x4* acc, const char* A, const char* B,
                                         int w, int l15, int lhi){
  #pragma unroll
  for (int ks = 0; ks < 4; ks++){
    const int kb = ks*64 + lhi*16;
    const uint4 a = *(const uint4*)(A + SW(w*16 + l15, kb));
    #pragma unroll
    for (int n = 0; n < 8; n++){
      const uint4 b = *(const uint4*)(B + SW(n*16 + l15, kb));
      acc[n] = MFMA(a, b, acc[n]);
    }
  }
}

// store frag-layout fp32 acc as bf16 tile: value (row=16w+4*lhi+q, col=16n+l15)
__device__ __forceinline__ void frag_store(char* buf, const f32x4* acc,
                                           int w, int l15, int lhi){
  #pragma unroll
  for (int n = 0; n < 8; n++)
    #pragma unroll
    for (int q = 0; q < 4; q++)
      *(unsigned short*)(buf + SW(w*16 + lhi*4 + q, 2*(n*16 + l15))) = f2b(acc[n][q]);
}

// stage 128x128 bf16 weight (row-major [n][k]) from global into swizzled LDS tile
__device__ __forceinline__ void stageW(char* W, const unsigned short* src, int tid){
  #pragma unroll
  for (int q = 0; q < 4; q++){
    const int chunk = q*512 + tid;          // 2048 chunks of 16B
    const int row = chunk >> 4, slot = chunk & 15;
    const uint4 v = *(const uint4*)(src + chunk*8);
    *(uint4*)(W + SW(row, slot*16)) = v;
  }
}

// coalesced LDS bf16 tile -> global fp32
__device__ __forceinline__ void tile_out(const char* buf, float* dst, int rt, int ct){
  #pragma unroll
  for (int i = 0; i < 4; i++){
    const int r = rt*4 + i;
    uint4 v = *(const uint4*)(buf + SW(r, 16*ct));
    float o[8]; unp8(v, o);
    *(float4*)(dst + (size_t)r*128 + ct*8)     = make_float4(o[0],o[1],o[2],o[3]);
    *(float4*)(dst + (size_t)r*128 + ct*8 + 4) = make_float4(o[4],o[5],o[6],o[7]);
  }
}

// ---- prep: wqkT[h][a] = bf16( sum_c wq[a][c]*wk[h][c] / sqrt(128) ) ----
__global__ __launch_bounds__(128) void prep_wqkT(const float* __restrict__ wq,
                                                 const float* __restrict__ wk,
                                                 unsigned short* __restrict__ ws16){
  __shared__ unsigned short wqb[128*130];
  __shared__ float wkr[128];
  const int h = blockIdx.x, t = threadIdx.x;
  for (int i = t; i < 16384; i += 128){ int a = i >> 7, c = i & 127; wqb[a*130+c] = f2b(wq[i]); }
  wkr[t] = wk[h*128 + t];
  __syncthreads();
  float s = 0.f;
  for (int c = 0; c < 128; c++) s += b2f(wqb[t*130 + c]) * wkr[c];
  ws16[h*128 + t] = f2b(s * 0.08838834764831845f);
}

// ---- prep: transpose+convert wv,w1,w2 -> ws16[16384 + i] ----
__global__ __launch_bounds__(256) void prep_T(const float* __restrict__ wv,
                                              const float* __restrict__ w1,
                                              const float* __restrict__ w2,
                                              unsigned short* __restrict__ ws16){
  const int i = blockIdx.x*256 + threadIdx.x;          // 0..49151
  const int which = i >> 14, r = i & 16383;
  const int hh = r >> 7, aa = r & 127;
  const float* s = (which == 0) ? wv : (which == 1) ? w1 : w2;
  ws16[16384 + i] = f2b(s[aa*128 + hh]);
}

__global__ void __launch_bounds__(NT, 1)
fused_gcn(const float* __restrict__ x, const float* __restrict__ mask,
          const float* __restrict__ theta, const float* __restrict__ w_t,
          const float* __restrict__ b_t, const unsigned short* __restrict__ ws16,
          const float* __restrict__ b1, const float* __restrict__ b2,
          const float* __restrict__ g_sa, const float* __restrict__ be_sa,
          const float* __restrict__ g_out, const float* __restrict__ be_out,
          float* __restrict__ out)
{
  extern __shared__ char smc[];
  char* Pb = smc + P_OFF;
  char* Qb = smc + Q_OFF;
  char* Rb = smc + R_OFF;
  char* Wb = smc + W_OFF;
  float* Xs  = (float*)(smc + XS_OFF);
  float* msh = (float*)(smc + MSH_OFF);
  float* nk  = (float*)(smc + NK_OFF);
  float* csum= (float*)(smc + CS_OFF);
  float* sN  = (float*)(smc + SN_OFF);
  float* Wf  = (float*)Wb;                 // theta[18][128] then w_t[18][128] (fp32, early)

  const int g    = blockIdx.x;
  const int tid  = threadIdx.x;
  const int lane = tid & 63;
  const int w    = tid >> 6;               // wave 0..7 -> rows 16w..16w+15
  const int l15  = lane & 15;
  const int lhi  = lane >> 4;
  const int rt = tid >> 4, ct = tid & 15;  // VALU-phase mapping: rows 4rt.., cols 8ct..
  const int r0 = rt << 2, h0 = ct << 3;

  const size_t gRH = (size_t)g * 16384;
  float* out0  = out;
  float* sa_o  = out + (size_t)Gg*128 + gRH;
  float* den_o = out + (size_t)Gg*128 + (size_t)Gg*16384 + gRH;
  float* att_o = out + (size_t)Gg*128 + 2*(size_t)Gg*16384 + gRH;
  float* adj_o = out + (size_t)Gg*128 + 3*(size_t)Gg*16384 + gRH;

  // ---- S0: stage x (f32), mask, theta+w_t (f32 into W) ----
  {
    const float* xg = x + (size_t)g * 2304;
    for (int i = tid; i < 2304; i += NT){ int r = i/18, f = i - r*18; Xs[r*20 + f] = xg[i]; }
    if (tid < 128) msh[tid] = mask[(size_t)g*128 + tid];
    for (int i = tid; i < 2304; i += NT) Wf[i] = theta[i];
    for (int i = tid; i < 2304; i += NT) Wf[2304 + i] = w_t[i];
  }
  __syncthreads();                                       // B0
  if (tid == 0){ float s = 0.f; for (int r = 0; r < 128; r++) s += msh[r]; *sN = s; }

  // ---- S1: adj (exact fp32) -> regs + adj_o; deg -> nk ----
  float av[4][8];
  {
    float sc0[8], sc1[8], snv[8], smv[8];
    #pragma unroll
    for (int j = 0; j < 8; j++){
      const int s = h0 + j;
      sc0[j] = Xs[s*20]; sc1[j] = Xs[s*20 + 1];
      snv[j] = sc0[j]*sc0[j] + sc1[j]*sc1[j];
      smv[j] = msh[s];
    }
    #pragma unroll
    for (int i = 0; i < 4; i++){
      const int r = r0 + i;
      const float c0 = Xs[r*20], c1 = Xs[r*20 + 1];
      const float nr = c0*c0 + c1*c1, mr = msh[r];
      float dsum = 0.f;
      #pragma unroll
      for (int j = 0; j < 8; j++){
        float dsq = nr + snv[j] - 2.f*(c0*sc0[j] + c1*sc1[j]);
        dsq = fminf(fmaxf(dsq, 1e-12f), 1e12f);
        const float a = expf(-sqrtf(dsq)) * mr * smv[j];
        av[i][j] = a; dsum += a;
      }
      #pragma unroll
      for (int o = 1; o < 16; o <<= 1) dsum += __shfl_xor(dsum, o);
      if (ct == 0){ const float t = dsum + 1e-6f; nk[r] = 1.f / (t * sqrtf(t)); }
      *(float4*)&adj_o[(size_t)r*128 + h0]     = make_float4(av[i][0],av[i][1],av[i][2],av[i][3]);
      *(float4*)&adj_o[(size_t)r*128 + h0 + 4] = make_float4(av[i][4],av[i][5],av[i][6],av[i][7]);
    }
  }
  __syncthreads();                                       // B1 (nk ready)

  // ---- S2: A' = adj^3 * nk[r]*nk[s] -> P (bf16) ----
  {
    float nkc[8];
    #pragma unroll
    for (int j = 0; j < 8; j++) nkc[j] = nk[h0 + j];
    #pragma unroll
    for (int i = 0; i < 4; i++){
      const float nr = nk[r0 + i];
      float tv[8];
      #pragma unroll
      for (int j = 0; j < 8; j++){ const float a = av[i][j]; tv[j] = a*a*a*nr*nkc[j]; }
      *(uint4*)(Pb + SW(r0 + i, 16*ct)) = pk8(tv);
    }
  }

  // ---- S3: f_het + gate (K=18 VALU); f_hetT -> Q; gate kept in regs ----
  float fh[4][8] = {}, gt[4][8] = {};
  {
    for (int k = 0; k < 18; k++){
      float xv[4];
      #pragma unroll
      for (int i = 0; i < 4; i++) xv[i] = Xs[(r0 + i)*20 + k];
      const float* th = &Wf[k*128 + h0];
      const float* wt = &Wf[2304 + k*128 + h0];
      const float4 t0 = *(const float4*)th, t1 = *(const float4*)(th + 4);
      const float4 g0 = *(const float4*)wt, g1 = *(const float4*)(wt + 4);
      const float tv[8] = {t0.x,t0.y,t0.z,t0.w,t1.x,t1.y,t1.z,t1.w};
      const float gv[8] = {g0.x,g0.y,g0.z,g0.w,g1.x,g1.y,g1.z,g1.w};
      #pragma unroll
      for (int i = 0; i < 4; i++)
        #pragma unroll
        for (int j = 0; j < 8; j++){ fh[i][j] += xv[i]*tv[j]; gt[i][j] += xv[i]*gv[j]; }
    }
    float btv[8];
    #pragma unroll
    for (int j = 0; j < 8; j++) btv[j] = b_t[h0 + j];
    #pragma unroll
    for (int i = 0; i < 4; i++)
      #pragma unroll
      for (int j = 0; j < 8; j++) gt[i][j] = 1.f / (1.f + expf(-(gt[i][j] + btv[j])));
    // f_hetT -> Q : Q[h][r] pairs (4B writes)
    #pragma unroll
    for (int j = 0; j < 8; j++){
      const int row = h0 + j;
      unsigned a = (unsigned)f2b(fh[0][j]) | ((unsigned)f2b(fh[1][j]) << 16);
      unsigned b = (unsigned)f2b(fh[2][j]) | ((unsigned)f2b(fh[3][j]) << 16);
      *(unsigned*)(Qb + SW(row, 8*rt))     = a;
      *(unsigned*)(Qb + SW(row, 8*rt + 4)) = b;
    }
  }
  __syncthreads();                                       // B2 (P=A', Q=f_hetT; Wf free)

  stageW(Wb, ws16, tid);                                 // wqkT (overlaps M2)

  // ---- M2: f_hom_pre = A' @ f_het ----
  f32x4 acc[8];
  #pragma unroll
  for (int n = 0; n < 8; n++){ f32x4 z = {0.f,0.f,0.f,0.f}; acc[n] = z; }
  mm_strip(acc, Pb, Qb, w, l15, lhi);
  __syncthreads();                                       // B3 (P,Q reads done)
  frag_store(Pb, acc, w, l15, lhi);                      // f_hom -> P
  __syncthreads();                                       // B4

  // ---- S5: og = gate*relu(f_hom) + (1-gate)*f_het -> R ; ogT -> Q ----
  {
    float ogv[4][8];
    #pragma unroll
    for (int i = 0; i < 4; i++){
      uint4 v = *(const uint4*)(Pb + SW(r0 + i, 16*ct));
      float fo[8]; unp8(v, fo);
      #pragma unroll
      for (int j = 0; j < 8; j++){
        const float gvx = gt[i][j];
        ogv[i][j] = gvx * fmaxf(fo[j], 0.f) + (1.f - gvx) * fh[i][j];
      }
      *(uint4*)(Rb + SW(r0 + i, 16*ct)) = pk8(ogv[i]);
    }
    #pragma unroll
    for (int j = 0; j < 8; j++){
      const int row = h0 + j;
      unsigned a = (unsigned)f2b(ogv[0][j]) | ((unsigned)f2b(ogv[1][j]) << 16);
      unsigned b = (unsigned)f2b(ogv[2][j]) | ((unsigned)f2b(ogv[3][j]) << 16);
      *(unsigned*)(Qb + SW(row, 8*rt))     = a;
      *(unsigned*)(Qb + SW(row, 8*rt + 4)) = b;
    }
  }
  __syncthreads();                                       // B5 (og, ogT, wqkT ready)

  // ---- M3: t = og @ wqk -> P ----
  #pragma unroll
  for (int n = 0; n < 8; n++){ f32x4 z = {0.f,0.f,0.f,0.f}; acc[n] = z; }
  mm_strip(acc, Rb, Wb, w, l15, lhi);
  frag_store(Pb, acc, w, l15, lhi);                      // own strip; P free since B5
  __syncthreads();                                       // B7 (W free)

  stageW(Wb, ws16 + 16384, tid);                         // wvT (overlaps M4/M5)

  // ---- M4: logits = t @ og^T ; masked softmax -> attn -> P (own strip) ----
  #pragma unroll
  for (int n = 0; n < 8; n++){ f32x4 z = {0.f,0.f,0.f,0.f}; acc[n] = z; }
  mm_strip(acc, Pb, Rb, w, l15, lhi);
  {
    float msv[8];
    #pragma unroll
    for (int n = 0; n < 8; n++) msv[n] = msh[16*n + l15];
    #pragma unroll
    for (int q = 0; q < 4; q++){
      const int row = 16*w + 4*lhi + q;
      float lv[8]; float mx = -3.4e38f;
      #pragma unroll
      for (int n = 0; n < 8; n++){
        lv[n] = acc[n][q] + (1.f - msv[n]) * (-1e9f);
        mx = fmaxf(mx, lv[n]);
      }
      #pragma unroll
      for (int o = 1; o < 16; o <<= 1) mx = fmaxf(mx, __shfl_xor(mx, o));
      float se = 0.f;
      #pragma unroll
      for (int n = 0; n < 8; n++){ lv[n] = expf(lv[n] - mx); se += lv[n]; }
      #pragma unroll
      for (int o = 1; o < 16; o <<= 1) se += __shfl_xor(se, o);
      const float inv = 1.f / se;
      #pragma unroll
      for (int n = 0; n < 8; n++)
        *(unsigned short*)(Pb + SW(row, 2*(16*n + l15))) = f2b(lv[n] * inv);
    }
  }
  __syncthreads();                                       // B8 (attn visible; R reads done)

  // ---- M5: u = attn @ og ; attn -> global ; u -> R ----
  #pragma unroll
  for (int n = 0; n < 8; n++){ f32x4 z = {0.f,0.f,0.f,0.f}; acc[n] = z; }
  mm_strip(acc, Pb, Qb, w, l15, lhi);
  tile_out(Pb, att_o, rt, ct);
  frag_store(Rb, acc, w, l15, lhi);                      // u -> R (R free since B8)
  __syncthreads();                                       // B10 (u + wvT ready)

  // ---- M6: sa = LN(u @ wv) * m -> Q + global ----
  #pragma unroll
  for (int n = 0; n < 8; n++){ f32x4 z = {0.f,0.f,0.f,0.f}; acc[n] = z; }
  mm_strip(acc, Rb, Wb, w, l15, lhi);
  {
    float gsa[8], bsa[8];
    #pragma unroll
    for (int n = 0; n < 8; n++){ const int c = 16*n + l15; gsa[n] = g_sa[c]; bsa[n] = be_sa[c]; }
    #pragma unroll
    for (int q = 0; q < 4; q++){
      const int row = 16*w + 4*lhi + q;
      float s1 = 0.f, s2 = 0.f;
      #pragma unroll
      for (int n = 0; n < 8; n++){ const float v = acc[n][q]; s1 += v; s2 += v*v; }
      #pragma unroll
      for (int o = 1; o < 16; o <<= 1){ s1 += __shfl_xor(s1, o); s2 += __shfl_xor(s2, o); }
      const float mean = s1 * 0.0078125f;
      const float var  = s2 * 0.0078125f - mean*mean;
      const float rstd = 1.f / sqrtf(var + 1e-3f);
      const float mr = msh[row];
      #pragma unroll
      for (int n = 0; n < 8; n++){
        const float y = ((acc[n][q] - mean) * rstd * gsa[n] + bsa[n]) * mr;
        *(unsigned short*)(Qb + SW(row, 2*(16*n + l15))) = f2b(y);   // Q free since B10
      }
    }
  }
  __syncthreads();                                       // B11 (sa ready; W free)

  stageW(Wb, ws16 + 32768, tid);                         // w1T
  tile_out(Qb, sa_o, rt, ct);                            // sa -> global
  __syncthreads();                                       // B12

  // ---- M7: d1 = relu(sa @ w1 + b1) -> P ----
  #pragma unroll
  for (int n = 0; n < 8; n++){ f32x4 z = {0.f,0.f,0.f,0.f}; acc[n] = z; }
  mm_strip(acc, Qb, Wb, w, l15, lhi);
  {
    float b1v[8];
    #pragma unroll
    for (int n = 0; n < 8; n++) b1v[n] = b1[16*n + l15];
    #pragma unroll
    for (int n = 0; n < 8; n++)
      #pragma unroll
      for (int q = 0; q < 4; q++)
        *(unsigned short*)(Pb + SW(16*w + 4*lhi + q, 2*(16*n + l15)))
            = f2b(fmaxf(acc[n][q] + b1v[n], 0.f));
  }
  __syncthreads();                                       // B13 (W free)
  stageW(Wb, ws16 + 49152, tid);                         // w2T
  __syncthreads();                                       // B14

  // ---- M8: d2=relu(d1@w2+b2); dense=LN(d2+sa)*m -> R + global; pool ----
  #pragma unroll
  for (int n = 0; n < 8; n++){ f32x4 z = {0.f,0.f,0.f,0.f}; acc[n] = z; }
  mm_strip(acc, Pb, Wb, w, l15, lhi);
  {
    float b2v[8], gov[8], bov[8], cs[8];
    #pragma unroll
    for (int n = 0; n < 8; n++){
      const int c = 16*n + l15;
      b2v[n] = b2[c]; gov[n] = g_out[c]; bov[n] = be_out[c]; cs[n] = 0.f;
    }
    #pragma unroll
    for (int q = 0; q < 4; q++){
      const int row = 16*w + 4*lhi + q;
      const float mr = msh[row];
      float dd[8];
      #pragma unroll
      for (int n = 0; n < 8; n++){
        const float sav = b2f(*(const unsigned short*)(Qb + SW(row, 2*(16*n + l15))));
        dd[n] = fmaxf(acc[n][q] + b2v[n], 0.f) + sav;
      }
      float s1 = 0.f, s2 = 0.f;
      #pragma unroll
      for (int n = 0; n < 8; n++){ s1 += dd[n]; s2 += dd[n]*dd[n]; }
      #pragma unroll
      for (int o = 1; o < 16; o <<= 1){ s1 += __shfl_xor(s1, o); s2 += __shfl_xor(s2, o); }
      const float mean = s1 * 0.0078125f;
      const float var  = s2 * 0.0078125f - mean*mean;
      const float rstd = 1.f / sqrtf(var + 1e-3f);
      #pragma unroll
      for (int n = 0; n < 8; n++){
        const float y = ((dd[n] - mean) * rstd * gov[n] + bov[n]) * mr;
        cs[n] += y;
        *(unsigned short*)(Rb + SW(row, 2*(16*n + l15))) = f2b(y);   // R free since B11
      }
    }
    #pragma unroll
    for (int n = 0; n < 8; n++){
      float v = cs[n];
      v += __shfl_xor(v, 16); v += __shfl_xor(v, 32);
      cs[n] = v;
    }
    if (lhi == 0)
      #pragma unroll
      for (int n = 0; n < 8; n++) csum[w*128 + 16*n + l15] = cs[n];
  }
  __syncthreads();                                       // B15

  tile_out(Rb, den_o, rt, ct);                           // dense -> global
  if (tid < 128){
    float s = 0.f;
    #pragma unroll
    for (int q = 0; q < 8; q++) s += csum[q*128 + tid];
    const float n = *sN;
    out0[(size_t)g*128 + tid] = (n > 0.f) ? (s / n) : 0.f;
  }
}

extern "C" void kernel_launch(void* const* d_in, const int* in_sizes, int n_in,
                              void* d_out, int out_size, void* d_ws, size_t ws_size,
                              hipStream_t stream) {
  (void)in_sizes; (void)n_in; (void)out_size; (void)ws_size;
  const float* x     = (const float*)d_in[0];
  const float* mask  = (const float*)d_in[1];
  const float* theta = (const float*)d_in[2];
  const float* w_t   = (const float*)d_in[3];
  const float* b_t   = (const float*)d_in[4];
  const float* wq    = (const float*)d_in[5];
  const float* wk    = (const float*)d_in[6];
  const float* wv    = (const float*)d_in[7];
  const float* w1    = (const float*)d_in[8];
  const float* b1    = (const float*)d_in[9];
  const float* w2    = (const float*)d_in[10];
  const float* b2    = (const float*)d_in[11];
  const float* g_sa  = (const float*)d_in[12];
  const float* be_sa = (const float*)d_in[13];
  const float* g_out = (const float*)d_in[14];
  const float* be_out= (const float*)d_in[15];
  unsigned short* ws16 = (unsigned short*)d_ws;   // 128 KiB: wqkT|wvT|w1T|w2T (bf16)

  prep_wqkT<<<dim3(128), dim3(128), 0, stream>>>(wq, wk, ws16);
  prep_T<<<dim3(192), dim3(256), 0, stream>>>(wv, w1, w2, ws16);

  (void)hipFuncSetAttribute(reinterpret_cast<const void*>(fused_gcn),
                            hipFuncAttributeMaxDynamicSharedMemorySize, SMEM_SZ);
  fused_gcn<<<dim3(Gg), dim3(NT), SMEM_SZ, stream>>>(
      x, mask, theta, w_t, b_t, ws16, b1, b2, g_sa, be_sa, g_out, be_out,
      (float*)d_out);
}

// Round 3
// 168.878 us; speedup vs baseline: 3.5818x; 1.1826x over previous
//
#include <hip/hip_runtime.h>
#include <math.h>

// RechitsGCN fused — round 3: 16 waves/block (pair-split n), MFMA K=18 path,
// fast-exp, no-max softmax, frag-direct f32 global stores.
#define Gg 1024
#define NT 1024

typedef __bf16 bf16x8 __attribute__((ext_vector_type(8)));
typedef float  f32x4  __attribute__((ext_vector_type(4)));

// ---- LDS byte map (149520 B dynamic) ----
#define P_OFF   0        // 32 KB bf16 tile (SW)
#define Q_OFF   32768    // 32 KB bf16 tile (SW)
#define R_OFF   65536    // 32 KB bf16 tile (SW)
#define W_OFF   98304    // 32 KB weight tile (SW); holds thetaT/w_tT (str80) early
#define XB_OFF  131072   // 128 x 32 bf16, stride 80 B
#define CO_OFF  141312   // 256 f32 coords
#define MS_OFF  142336   // 128 f32 mask
#define NK_OFF  142848   // 128 f32
#define CS_OFF  143360   // 512 f32 cross-pair reduce
#define PL_OFF  145408   // 1024 f32 pool
#define SN_OFF  149504
#define SMEM_SZ 149520

__device__ __forceinline__ unsigned short f2b(float f){
  unsigned u = __float_as_uint(f);
  u += 0x7FFFu + ((u >> 16) & 1u);
  return (unsigned short)(u >> 16);
}
__device__ __forceinline__ float b2f(unsigned short h){
  return __uint_as_float(((unsigned)h) << 16);
}
__device__ __forceinline__ int SW(int row, int bc){ return (row << 8) + (bc ^ ((row & 7) << 4)); }

__device__ __forceinline__ uint4 pk8(const float* f){
  uint4 v;
  v.x = (unsigned)f2b(f[0]) | ((unsigned)f2b(f[1])<<16);
  v.y = (unsigned)f2b(f[2]) | ((unsigned)f2b(f[3])<<16);
  v.z = (unsigned)f2b(f[4]) | ((unsigned)f2b(f[5])<<16);
  v.w = (unsigned)f2b(f[6]) | ((unsigned)f2b(f[7])<<16);
  return v;
}
__device__ __forceinline__ f32x4 MFMA(uint4 a, uint4 b, f32x4 c){
  return __builtin_amdgcn_mfma_f32_16x16x32_bf16(
      __builtin_bit_cast(bf16x8, a), __builtin_bit_cast(bf16x8, b), c, 0, 0, 0);
}
#define ZACC(A) { f32x4 z_={0.f,0.f,0.f,0.f}; A[0]=z_; A[1]=z_; A[2]=z_; A[3]=z_; }

// D strip(16 rows of pair p, 64 cols of sub) = A(128x128) @ B_storage^T, K=128
__device__ __forceinline__ void mm_full(f32x4* acc, const char* A, const char* B,
                                        int p, int sub, int l15, int lhi){
  #pragma unroll
  for (int ks = 0; ks < 4; ks++){
    const int kb = ks*64 + lhi*16;
    const uint4 a = *(const uint4*)(A + SW(16*p + l15, kb));
    #pragma unroll
    for (int n0 = 0; n0 < 4; n0++){
      const uint4 b = *(const uint4*)(B + SW((sub*4 + n0)*16 + l15, kb));
      acc[n0] = MFMA(a, b, acc[n0]);
    }
  }
}
// K=32 (padded 18) from stride-80 buffers
__device__ __forceinline__ void mmX(f32x4* acc, const char* Xb, const char* Wt,
                                    int p, int sub, int l15, int lhi){
  const uint4 a = *(const uint4*)(Xb + 80*(16*p + l15) + lhi*16);
  #pragma unroll
  for (int n0 = 0; n0 < 4; n0++){
    const uint4 b = *(const uint4*)(Wt + 80*((sub*4 + n0)*16 + l15) + lhi*16);
    acc[n0] = MFMA(a, b, acc[n0]);
  }
}
__device__ __forceinline__ void frag_store(char* buf, const f32x4* acc,
                                           int p, int sub, int l15, int lhi){
  #pragma unroll
  for (int n0 = 0; n0 < 4; n0++){
    const int col = (sub*4 + n0)*16 + l15;
    #pragma unroll
    for (int q = 0; q < 4; q++)
      *(unsigned short*)(buf + SW(16*p + 4*lhi + q, 2*col)) = f2b(acc[n0][q]);
  }
}
// transposed store: buf[col][row], 4 rows packed per 8B write
__device__ __forceinline__ void fragT_store(char* buf, const f32x4* acc,
                                            int p, int sub, int l15, int lhi){
  const int row0 = 16*p + 4*lhi;
  #pragma unroll
  for (int n0 = 0; n0 < 4; n0++){
    const int col = (sub*4 + n0)*16 + l15;
    uint2 u;
    u.x = (unsigned)f2b(acc[n0][0]) | ((unsigned)f2b(acc[n0][1])<<16);
    u.y = (unsigned)f2b(acc[n0][2]) | ((unsigned)f2b(acc[n0][3])<<16);
    *(uint2*)(buf + SW(col, 2*row0)) = u;
  }
}
__device__ __forceinline__ void stageW(char* W, const unsigned short* src, int tid){
  #pragma unroll
  for (int q = 0; q < 2; q++){
    const int chunk = q*NT + tid;
    const uint4 v = *(const uint4*)(src + chunk*8);
    *(uint4*)(W + SW(chunk >> 4, (chunk & 15)*16)) = v;
  }
}
__device__ __forceinline__ void loadW(uint4* r, const unsigned short* src, int tid){
  r[0] = *(const uint4*)(src + (size_t)tid*8);
  r[1] = *(const uint4*)(src + (size_t)(NT + tid)*8);
}
__device__ __forceinline__ void writeW(char* W, const uint4* r, int tid){
  *(uint4*)(W + SW(tid >> 4, (tid & 15)*16)) = r[0];
  *(uint4*)(W + SW((NT + tid) >> 4, ((NT + tid) & 15)*16)) = r[1];
}

// ---- prep: wqkT[h][a] = bf16( sum_c wq[a][c]*wk[h][c] / sqrt(128) ) ----
__global__ __launch_bounds__(128) void prep_wqkT(const float* __restrict__ wq,
                                                 const float* __restrict__ wk,
                                                 unsigned short* __restrict__ ws16){
  __shared__ unsigned short wqb[128*130];
  __shared__ float wkr[128];
  const int h = blockIdx.x, t = threadIdx.x;
  for (int i = t; i < 16384; i += 128){ int a = i >> 7, c = i & 127; wqb[a*130+c] = f2b(wq[i]); }
  wkr[t] = wk[h*128 + t];
  __syncthreads();
  float s = 0.f;
  for (int c = 0; c < 128; c++) s += b2f(wqb[t*130 + c]) * wkr[c];
  ws16[h*128 + t] = f2b(s * 0.08838834764831845f);
}

// ---- prep: wvT|w1T|w2T (16384..), thetaT|w_tT K=32-padded (65536..) ----
__global__ __launch_bounds__(256) void prep_T(const float* __restrict__ wv,
                                              const float* __restrict__ w1,
                                              const float* __restrict__ w2,
                                              const float* __restrict__ theta,
                                              const float* __restrict__ w_t,
                                              unsigned short* __restrict__ ws16){
  const int i = blockIdx.x*256 + threadIdx.x;
  if (i < 49152){
    const int which = i >> 14, r = i & 16383;
    const int hh = r >> 7, aa = r & 127;
    const float* s = (which == 0) ? wv : (which == 1) ? w1 : w2;
    ws16[16384 + i] = f2b(s[aa*128 + hh]);
  } else if (i < 57344){
    const int t2 = i - 49152;
    const int mat = t2 >> 12, r = t2 & 4095;
    const int hh = r >> 5, kk = r & 31;
    const float* s = (mat == 0) ? theta : w_t;
    ws16[16384 + i] = (kk < 18) ? f2b(s[kk*128 + hh]) : (unsigned short)0;
  }
}

__global__ void __launch_bounds__(NT, 1)
fused_gcn(const float* __restrict__ x, const float* __restrict__ mask,
          const float* __restrict__ b_t, const unsigned short* __restrict__ ws16,
          const float* __restrict__ b1, const float* __restrict__ b2,
          const float* __restrict__ g_sa, const float* __restrict__ be_sa,
          const float* __restrict__ g_out, const float* __restrict__ be_out,
          float* __restrict__ out)
{
  extern __shared__ char smc[];
  char* Pb = smc + P_OFF;
  char* Qb = smc + Q_OFF;
  char* Rb = smc + R_OFF;
  char* Wb = smc + W_OFF;
  char* Xb = smc + XB_OFF;
  float* coords = (float*)(smc + CO_OFF);
  float* msh    = (float*)(smc + MS_OFF);
  float* nk     = (float*)(smc + NK_OFF);
  float* csum   = (float*)(smc + CS_OFF);
  float* pool   = (float*)(smc + PL_OFF);
  float* sN     = (float*)(smc + SN_OFF);

  const int g    = blockIdx.x;
  const int tid  = threadIdx.x;
  const int lane = tid & 63;
  const int wv_  = tid >> 6;            // wave 0..15
  const int p    = wv_ >> 1;            // pair 0..7: rows 16p..16p+15
  const int sub  = wv_ & 1;             // n-half
  const int l15  = lane & 15;
  const int lhi  = lane >> 4;
  const int rt2  = tid >> 4;            // VALU map: rows {2rt2, 2rt2+1}
  const int ct   = tid & 15;            // cols 8ct..8ct+7

  const size_t gRH = (size_t)g * 16384;
  float* out0  = out;
  float* sa_o  = out + (size_t)Gg*128 + gRH;
  float* den_o = out + (size_t)Gg*128 + (size_t)Gg*16384 + gRH;
  float* att_o = out + (size_t)Gg*128 + 2*(size_t)Gg*16384 + gRH;
  float* adj_o = out + (size_t)Gg*128 + 3*(size_t)Gg*16384 + gRH;

  // ---- S0: stage x->Xb bf16 (str80, zero-pad k>=18), coords, mask, thetaT/w_tT->W
  {
    const float* xg = x + (size_t)g * 2304;
    for (int i = tid; i < 2304; i += NT){
      const int r = i / 18, k = i - r*18;
      *(unsigned short*)(Xb + r*80 + k*2) = f2b(xg[i]);
    }
    if (tid < 128){
      #pragma unroll
      for (int c = 18; c < 32; c += 2) *(unsigned*)(Xb + tid*80 + c*2) = 0u;
      msh[tid] = mask[(size_t)g*128 + tid];
    }
    if (tid < 256) coords[tid] = xg[(tid >> 1)*18 + (tid & 1)];
    {
      const int which = tid >> 9, t = tid & 511;
      const uint4 v = *(const uint4*)(ws16 + 65536 + which*4096 + t*8);
      *(uint4*)(Wb + which*10240 + (t >> 2)*80 + (t & 3)*16) = v;
    }
  }
  __syncthreads();                                       // B0
  if (tid == 0){ float s = 0.f; for (int r = 0; r < 128; r++) s += msh[r]; *sN = s; }

  // ---- S3 (MFMA): f_het = X@theta, gate = sigmoid(X@w_t + b_t); f_hetT -> Q
  f32x4 fhet[4]; float gate[4][4];
  {
    f32x4 gf[4];
    ZACC(fhet); ZACC(gf);
    mmX(fhet, Xb, Wb, p, sub, l15, lhi);
    mmX(gf,   Xb, Wb + 10240, p, sub, l15, lhi);
    #pragma unroll
    for (int n0 = 0; n0 < 4; n0++){
      const float btv = b_t[(sub*4 + n0)*16 + l15];
      #pragma unroll
      for (int q = 0; q < 4; q++)
        gate[n0][q] = 1.f / (1.f + __expf(-(gf[n0][q] + btv)));
    }
    fragT_store(Qb, fhet, p, sub, l15, lhi);
  }

  // ---- S1: adj exact f32 -> adj_o + regs; deg -> nk ----
  float av[2][8];
  {
    float sc0[8], sc1[8], smv[8];
    #pragma unroll
    for (int j = 0; j < 8; j++){
      const int s = 8*ct + j;
      sc0[j] = coords[2*s]; sc1[j] = coords[2*s + 1]; smv[j] = msh[s];
    }
    #pragma unroll
    for (int i = 0; i < 2; i++){
      const int r = 2*rt2 + i;
      const float c0 = coords[2*r], c1 = coords[2*r + 1];
      const float mr = msh[r];
      float dsum = 0.f;
      #pragma unroll
      for (int j = 0; j < 8; j++){
        const float dx = c0 - sc0[j], dy = c1 - sc1[j];
        float dsq = dx*dx + dy*dy;
        dsq = fminf(fmaxf(dsq, 1e-12f), 1e12f);
        const float a = __expf(-__fsqrt_rn(dsq)) * (mr * smv[j]);
        av[i][j] = a; dsum += a;
      }
      #pragma unroll
      for (int o = 1; o < 16; o <<= 1) dsum += __shfl_xor(dsum, o);
      if (ct == 0){ const float t = dsum + 1e-6f; const float rs = __frsqrt_rn(t); nk[r] = rs*rs*rs; }
      *(float4*)&adj_o[(size_t)r*128 + 8*ct]     = make_float4(av[i][0],av[i][1],av[i][2],av[i][3]);
      *(float4*)&adj_o[(size_t)r*128 + 8*ct + 4] = make_float4(av[i][4],av[i][5],av[i][6],av[i][7]);
    }
  }
  __syncthreads();                                       // B1 (nk ready; Q f_hetT done)

  // ---- S2: A' = adj^3 * nk[r]*nk[s] -> P ----
  {
    float nkc[8];
    #pragma unroll
    for (int j = 0; j < 8; j++) nkc[j] = nk[8*ct + j];
    #pragma unroll
    for (int i = 0; i < 2; i++){
      const int r = 2*rt2 + i;
      const float nr = nk[r];
      float tv[8];
      #pragma unroll
      for (int j = 0; j < 8; j++){ const float a = av[i][j]; tv[j] = a*a*a*nr*nkc[j]; }
      *(uint4*)(Pb + SW(r, 16*ct)) = pk8(tv);
    }
  }
  __syncthreads();                                       // B2

  stageW(Wb, ws16, tid);                                 // wqkT (overlaps M2)

  // ---- M2: f_hom_pre = A' @ f_het (regs) ----
  f32x4 acc[4];
  ZACC(acc);
  mm_full(acc, Pb, Qb, p, sub, l15, lhi);
  __syncthreads();                                       // B4 (P,Q reads done)

  // ---- S5: og = gate*relu(f_hom)+(1-gate)*f_het -> R (row) + Q (ogT) ----
  {
    f32x4 ogv[4];
    #pragma unroll
    for (int n0 = 0; n0 < 4; n0++)
      #pragma unroll
      for (int q = 0; q < 4; q++){
        const float gv = gate[n0][q];
        ogv[n0][q] = gv * fmaxf(acc[n0][q], 0.f) + (1.f - gv) * fhet[n0][q];
      }
    frag_store(Rb, ogv, p, sub, l15, lhi);
    fragT_store(Qb, ogv, p, sub, l15, lhi);
  }
  __syncthreads();                                       // B5

  // ---- M3: t = og @ wqk -> P ----
  ZACC(acc);
  mm_full(acc, Rb, Wb, p, sub, l15, lhi);
  frag_store(Pb, acc, p, sub, l15, lhi);
  __syncthreads();                                       // B6

  stageW(Wb, ws16 + 16384, tid);                         // wvT (overlaps M4/M5)

  // ---- M4: logits = t @ og^T ; no-max masked softmax (cross-pair via csum) ----
  ZACC(acc);
  mm_full(acc, Pb, Rb, p, sub, l15, lhi);
  float ee[4][4];
  {
    float msv[4];
    #pragma unroll
    for (int n0 = 0; n0 < 4; n0++) msv[n0] = msh[(sub*4 + n0)*16 + l15];
    #pragma unroll
    for (int q = 0; q < 4; q++){
      const int row = 16*p + 4*lhi + q;
      float se = 0.f;
      #pragma unroll
      for (int n0 = 0; n0 < 4; n0++){
        const float e = __expf(acc[n0][q]) * msv[n0];
        ee[n0][q] = e; se += e;
      }
      #pragma unroll
      for (int o = 1; o < 16; o <<= 1) se += __shfl_xor(se, o);
      if (l15 == 0) csum[row*2 + sub] = se;
    }
  }
  __syncthreads();                                       // B7 (all M4 reads done)
  #pragma unroll
  for (int q = 0; q < 4; q++){
    const int row = 16*p + 4*lhi + q;
    const float inv = 1.f / (csum[row*2] + csum[row*2 + 1]);
    #pragma unroll
    for (int n0 = 0; n0 < 4; n0++){
      const float a = ee[n0][q] * inv;
      const int col = (sub*4 + n0)*16 + l15;
      att_o[(size_t)row*128 + col] = a;                  // f32 exact
      *(unsigned short*)(Pb + SW(row, 2*col)) = f2b(a);
    }
  }
  __syncthreads();                                       // B8 (attn tile complete)

  uint4 w1r[2];
  loadW(w1r, ws16 + 32768, tid);                         // w1T -> regs (in flight)

  // ---- M5: u = attn @ og -> R ----
  ZACC(acc);
  mm_full(acc, Pb, Qb, p, sub, l15, lhi);
  frag_store(Rb, acc, p, sub, l15, lhi);
  __syncthreads();                                       // B9

  // ---- M6: sa = LN(u @ wv)*m -> Q + global + regs ----
  ZACC(acc);
  mm_full(acc, Rb, Wb, p, sub, l15, lhi);
  f32x4 sav[4];
  {
    #pragma unroll
    for (int q = 0; q < 4; q++){
      const int row = 16*p + 4*lhi + q;
      float s1 = 0.f, s2 = 0.f;
      #pragma unroll
      for (int n0 = 0; n0 < 4; n0++){ const float v = acc[n0][q]; s1 += v; s2 += v*v; }
      #pragma unroll
      for (int o = 1; o < 16; o <<= 1){ s1 += __shfl_xor(s1, o); s2 += __shfl_xor(s2, o); }
      if (l15 == 0){ csum[row*4 + sub*2] = s1; csum[row*4 + sub*2 + 1] = s2; }
    }
  }
  __syncthreads();                                       // B10
  {
    float gsa[4], bsa[4];
    #pragma unroll
    for (int n0 = 0; n0 < 4; n0++){ const int c = (sub*4+n0)*16 + l15; gsa[n0] = g_sa[c]; bsa[n0] = be_sa[c]; }
    #pragma unroll
    for (int q = 0; q < 4; q++){
      const int row = 16*p + 4*lhi + q;
      const float s1 = csum[row*4] + csum[row*4 + 2];
      const float s2 = csum[row*4 + 1] + csum[row*4 + 3];
      const float mean = s1 * 0.0078125f;
      const float var  = s2 * 0.0078125f - mean*mean;
      const float rstd = __frsqrt_rn(var + 1e-3f);
      const float mr = msh[row];
      #pragma unroll
      for (int n0 = 0; n0 < 4; n0++){
        const float y = ((acc[n0][q] - mean) * rstd * gsa[n0] + bsa[n0]) * mr;
        sav[n0][q] = y;
        sa_o[(size_t)row*128 + (sub*4+n0)*16 + l15] = y;  // f32 exact
      }
    }
    frag_store(Qb, sav, p, sub, l15, lhi);
  }
  __syncthreads();                                       // B11 (W reads done)
  writeW(Wb, w1r, tid);                                  // w1T -> LDS
  __syncthreads();                                       // B12

  // ---- M7: d1 = relu(sa @ w1 + b1) -> P ----
  ZACC(acc);
  mm_full(acc, Qb, Wb, p, sub, l15, lhi);
  {
    f32x4 d1v[4];
    #pragma unroll
    for (int n0 = 0; n0 < 4; n0++){
      const float b1v = b1[(sub*4 + n0)*16 + l15];
      #pragma unroll
      for (int q = 0; q < 4; q++) d1v[n0][q] = fmaxf(acc[n0][q] + b1v, 0.f);
    }
    frag_store(Pb, d1v, p, sub, l15, lhi);
  }
  uint4 w2r[2];
  loadW(w2r, ws16 + 49152, tid);                         // w2T -> regs
  __syncthreads();                                       // B13
  writeW(Wb, w2r, tid);
  __syncthreads();                                       // B14

  // ---- M8: d2=relu(d1@w2+b2); dense=LN(d2+sa)*m -> global; masked mean pool ----
  ZACC(acc);
  mm_full(acc, Pb, Wb, p, sub, l15, lhi);
  {
    float b2v[4], gov[4], bov[4], dd[4][4];
    #pragma unroll
    for (int n0 = 0; n0 < 4; n0++){
      const int c = (sub*4 + n0)*16 + l15;
      b2v[n0] = b2[c]; gov[n0] = g_out[c]; bov[n0] = be_out[c];
    }
    #pragma unroll
    for (int q = 0; q < 4; q++){
      const int row = 16*p + 4*lhi + q;
      float s1 = 0.f, s2 = 0.f;
      #pragma unroll
      for (int n0 = 0; n0 < 4; n0++){
        const float v = fmaxf(acc[n0][q] + b2v[n0], 0.f) + sav[n0][q];
        dd[n0][q] = v; s1 += v; s2 += v*v;
      }
      #pragma unroll
      for (int o = 1; o < 16; o <<= 1){ s1 += __shfl_xor(s1, o); s2 += __shfl_xor(s2, o); }
      if (l15 == 0){ csum[row*4 + sub*2] = s1; csum[row*4 + sub*2 + 1] = s2; }
    }
    __syncthreads();                                     // B15
    float cs[4] = {0.f, 0.f, 0.f, 0.f};
    #pragma unroll
    for (int q = 0; q < 4; q++){
      const int row = 16*p + 4*lhi + q;
      const float s1 = csum[row*4] + csum[row*4 + 2];
      const float s2 = csum[row*4 + 1] + csum[row*4 + 3];
      const float mean = s1 * 0.0078125f;
      const float var  = s2 * 0.0078125f - mean*mean;
      const float rstd = __frsqrt_rn(var + 1e-3f);
      const float mr = msh[row];
      #pragma unroll
      for (int n0 = 0; n0 < 4; n0++){
        const float y = ((dd[n0][q] - mean) * rstd * gov[n0] + bov[n0]) * mr;
        den_o[(size_t)row*128 + (sub*4+n0)*16 + l15] = y;  // f32 exact
        cs[n0] += y;
      }
    }
    #pragma unroll
    for (int n0 = 0; n0 < 4; n0++){
      float v = cs[n0];
      v += __shfl_xor(v, 16); v += __shfl_xor(v, 32);
      if (lhi == 0) pool[p*128 + (sub*4 + n0)*16 + l15] = v;
    }
  }
  __syncthreads();                                       // B16
  if (tid < 128){
    float s = 0.f;
    #pragma unroll
    for (int q = 0; q < 8; q++) s += pool[q*128 + tid];
    const float n = *sN;
    out0[(size_t)g*128 + tid] = (n > 0.f) ? (s / n) : 0.f;
  }
}

extern "C" void kernel_launch(void* const* d_in, const int* in_sizes, int n_in,
                              void* d_out, int out_size, void* d_ws, size_t ws_size,
                              hipStream_t stream) {
  (void)in_sizes; (void)n_in; (void)out_size; (void)ws_size;
  const float* x     = (const float*)d_in[0];
  const float* mask  = (const float*)d_in[1];
  const float* theta = (const float*)d_in[2];
  const float* w_t   = (const float*)d_in[3];
  const float* b_t   = (const float*)d_in[4];
  const float* wq    = (const float*)d_in[5];
  const float* wk    = (const float*)d_in[6];
  const float* wvp   = (const float*)d_in[7];
  const float* w1    = (const float*)d_in[8];
  const float* b1    = (const float*)d_in[9];
  const float* w2    = (const float*)d_in[10];
  const float* b2    = (const float*)d_in[11];
  const float* g_sa  = (const float*)d_in[12];
  const float* be_sa = (const float*)d_in[13];
  const float* g_out = (const float*)d_in[14];
  const float* be_out= (const float*)d_in[15];
  unsigned short* ws16 = (unsigned short*)d_ws;  // 144 KiB: wqkT|wvT|w1T|w2T|thetaT|w_tT

  prep_wqkT<<<dim3(128), dim3(128), 0, stream>>>(wq, wk, ws16);
  prep_T<<<dim3(224), dim3(256), 0, stream>>>(wvp, w1, w2, theta, w_t, ws16);

  (void)hipFuncSetAttribute(reinterpret_cast<const void*>(fused_gcn),
                            hipFuncAttributeMaxDynamicSharedMemorySize, SMEM_SZ);
  fused_gcn<<<dim3(Gg), dim3(NT), SMEM_SZ, stream>>>(
      x, mask, b_t, ws16, b1, b2, g_sa, be_sa, g_out, be_out, (float*)d_out);
}